// Round 4
// baseline (1388.825 us; speedup 1.0000x reference)
//
#include <hip/hip_runtime.h>
#include <hip/hip_fp16.h>

// HyperScatteringModule: V=65536, E=16384, NNZ=1048576, F=128
#define FEAT 128

// ---------------- fp16 helpers (packed in dwords: lo = even feat) ----------------

__device__ inline float hlo(unsigned u) {
    unsigned short s = (unsigned short)(u & 0xFFFFu);
    __half h = *(__half*)&s;
    return __half2float(h);
}
__device__ inline float hhi(unsigned u) {
    unsigned short s = (unsigned short)(u >> 16);
    __half h = *(__half*)&s;
    return __half2float(h);
}
__device__ inline unsigned hpack(float a, float b) {
    __half ha = __float2half_rn(a), hb = __float2half_rn(b);
    unsigned short ua = *(unsigned short*)&ha, ub = *(unsigned short*)&hb;
    return (unsigned)ua | ((unsigned)ub << 16);
}
__device__ inline unsigned pkadd(unsigned a, unsigned b) {
    __half2 ha = *(__half2*)&a, hb = *(__half2*)&b;
    __half2 r = __hadd2(ha, hb);
    return *(unsigned*)&r;
}

// ---------------- CSR build ----------------

__global__ void count_deg(const int* __restrict__ vids, const int* __restrict__ eids,
                          int* __restrict__ deg_v, int* __restrict__ deg_e, int nnz) {
    int n = blockIdx.x * blockDim.x + threadIdx.x;
    if (n < nnz) {
        atomicAdd(&deg_v[vids[n]], 1);
        atomicAdd(&deg_e[eids[n]], 1);
    }
}

// Exclusive scan over CHUNK-padded degrees; off/cur = padded offsets, inv = 1/true_deg.
template <int N, int T, int CHUNK>
__global__ __launch_bounds__(T) void scan_pad(const int* __restrict__ deg,
                                              int* __restrict__ off,
                                              int* __restrict__ cur,
                                              float* __restrict__ inv) {
    __shared__ int partial[T];
    const int per = N / T;
    int tid = threadIdx.x;
    int base = tid * per;
    int dloc[per];
    int s = 0;
#pragma unroll
    for (int i = 0; i < per / 4; ++i) {
        int4 d4 = *(const int4*)(deg + base + 4 * i);
        dloc[4 * i] = d4.x; dloc[4 * i + 1] = d4.y;
        dloc[4 * i + 2] = d4.z; dloc[4 * i + 3] = d4.w;
        s += ((d4.x + CHUNK - 1) & ~(CHUNK - 1)) + ((d4.y + CHUNK - 1) & ~(CHUNK - 1)) +
             ((d4.z + CHUNK - 1) & ~(CHUNK - 1)) + ((d4.w + CHUNK - 1) & ~(CHUNK - 1));
    }
    partial[tid] = s;
    __syncthreads();
    for (int d = 1; d < T; d <<= 1) {
        int add = (tid >= d) ? partial[tid - d] : 0;
        __syncthreads();
        partial[tid] += add;
        __syncthreads();
    }
    int run = (tid > 0) ? partial[tid - 1] : 0;
#pragma unroll
    for (int i = 0; i < per / 4; ++i) {
        int o[4];
        float iv[4];
#pragma unroll
        for (int j = 0; j < 4; ++j) {
            int d = dloc[4 * i + j];
            o[j] = run;
            iv[j] = (d > 0) ? (1.0f / (float)d) : 0.0f;
            run += (d + CHUNK - 1) & ~(CHUNK - 1);
        }
        *(int4*)(off + base + 4 * i) = make_int4(o[0], o[1], o[2], o[3]);
        *(int4*)(cur + base + 4 * i) = make_int4(o[0], o[1], o[2], o[3]);
        *(float4*)(inv + base + 4 * i) = make_float4(iv[0], iv[1], iv[2], iv[3]);
    }
    if (tid == T - 1) off[N] = run;
}

// Fill padded slots with dummy row indices; zero the dummy rows of xs/es.
__global__ void init_pad(int* __restrict__ nbrE, int nE, int dummyE,
                         int* __restrict__ nbrV, int nV, int dummyV,
                         unsigned* __restrict__ xzero, unsigned* __restrict__ ezero) {
    int i = blockIdx.x * 256 + threadIdx.x;
    if (i < nE) nbrE[i] = dummyE;
    if (i < nV) nbrV[i] = dummyV;
    if (i < 64) { xzero[i] = 0u; ezero[i] = 0u; }
}

__global__ void fill_csr(const int* __restrict__ vids, const int* __restrict__ eids,
                         int* __restrict__ cur_v, int* __restrict__ cur_e,
                         int* __restrict__ v_nbr_e, int* __restrict__ e_nbr_v, int nnz) {
    int n = blockIdx.x * blockDim.x + threadIdx.x;
    if (n < nnz) {
        int v = vids[n], e = eids[n];
        int p = atomicAdd(&cur_e[e], 1);
        e_nbr_v[p] = v;
        int q = atomicAdd(&cur_v[v], 1);
        v_nbr_e[q] = e;
    }
}

// ---------------- prescale: xs = fp16(X * inv_v) ----------------
__global__ __launch_bounds__(256) void prescale(const float* __restrict__ X,
                                                const float* __restrict__ inv_v,
                                                unsigned* __restrict__ xs) {
    int i = blockIdx.x * 256 + threadIdx.x;  // dword index over V*64
    float sc = inv_v[i >> 6];
    float2 x = *(const float2*)(X + 2 * (long)i);
    xs[i] = hpack(x.x * sc, x.y * sc);
}

// ---------------- padded segment gather-sum, 4 rows per dwordx4 load ----------------
// Lane-groups (lane>>4) each own one row of a quad; lane reads 16B (4 dwords =
// 8 fp16 feats) of that row at dword-quad (lane&15). Packed fp16 accumulation;
// butterfly across groups at segment end; each lane stores one scaled dword.
// Neighbor lists are CHUNK-padded with dummy zero-row indices.
template <int CHUNK, int SPW>
__global__ __launch_bounds__(256) void gather4(const unsigned* __restrict__ src,
                                               const int* __restrict__ offs,
                                               const int* __restrict__ nbr,
                                               const float* __restrict__ scale,
                                               unsigned* __restrict__ dst,
                                               unsigned* __restrict__ ckpt,
                                               int nseg) {
    int wv = __builtin_amdgcn_readfirstlane(blockIdx.x * 4 + (threadIdx.x >> 6));
    int lane = threadIdx.x & 63;
    int sub = lane & 15;          // dword-quad within row
    bool m16 = (lane & 16) != 0;
    bool m32 = (lane & 32) != 0;
    int boff = sub << 4;          // byte offset within row
    const char* srcb = (const char*)src;
    int seg0 = wv * SPW;
    if (seg0 >= nseg) return;
    int p = offs[seg0];
#pragma unroll
    for (int i = 0; i < SPW; ++i) {
        int s = seg0 + i;
        int pend = offs[s + 1];
        unsigned a0 = 0u, a1 = 0u, a2 = 0u, a3 = 0u;
        while (p < pend) {
            int4 c0 = *(const int4*)(nbr + p);
            int u0 = m32 ? (m16 ? c0.w : c0.z) : (m16 ? c0.y : c0.x);
            uint4 r0 = *(const uint4*)(srcb + (((size_t)(unsigned)u0) << 8) + boff);
            if (CHUNK == 8) {
                int4 c1 = *(const int4*)(nbr + p + 4);
                int u1 = m32 ? (m16 ? c1.w : c1.z) : (m16 ? c1.y : c1.x);
                uint4 r1 = *(const uint4*)(srcb + (((size_t)(unsigned)u1) << 8) + boff);
                a0 = pkadd(a0, r0.x); a1 = pkadd(a1, r0.y);
                a2 = pkadd(a2, r0.z); a3 = pkadd(a3, r0.w);
                a0 = pkadd(a0, r1.x); a1 = pkadd(a1, r1.y);
                a2 = pkadd(a2, r1.z); a3 = pkadd(a3, r1.w);
            } else {
                a0 = pkadd(a0, r0.x); a1 = pkadd(a1, r0.y);
                a2 = pkadd(a2, r0.z); a3 = pkadd(a3, r0.w);
            }
            p += CHUNK;
        }
        // butterfly: sum the 4 lane-groups (xor 16, then xor 32)
        a0 = pkadd(a0, (unsigned)__shfl_xor((int)a0, 16, 64));
        a1 = pkadd(a1, (unsigned)__shfl_xor((int)a1, 16, 64));
        a2 = pkadd(a2, (unsigned)__shfl_xor((int)a2, 16, 64));
        a3 = pkadd(a3, (unsigned)__shfl_xor((int)a3, 16, 64));
        a0 = pkadd(a0, (unsigned)__shfl_xor((int)a0, 32, 64));
        a1 = pkadd(a1, (unsigned)__shfl_xor((int)a1, 32, 64));
        a2 = pkadd(a2, (unsigned)__shfl_xor((int)a2, 32, 64));
        a3 = pkadd(a3, (unsigned)__shfl_xor((int)a3, 32, 64));
        // lane stores dword sub*4 + grp: select a_grp
        unsigned t0 = m16 ? a1 : a0;
        unsigned t1 = m16 ? a3 : a2;
        unsigned d = m32 ? t1 : t0;
        float sc = scale[s];
        unsigned pk = hpack(hlo(d) * sc, hhi(d) * sc);
        int dofs = (sub << 2) + (m32 ? 2 : 0) + (m16 ? 1 : 0);
        dst[(size_t)s * 64 + dofs] = pk;
        if (ckpt) ckpt[(size_t)s * 1536 + dofs] = pk;
    }
}

// ---------------- final wavelet combine + relu split ----------------
// Checkpoints are fp16(inv_v * L) packed at out dword offset v*1536 + slot*256 + [0,64);
// recover L = ckpt * deg_v. 256 threads = 8 vertices; read all, sync, write.
__global__ __launch_bounds__(256) void wavelet_out(const float* __restrict__ X,
                                                   const int* __restrict__ deg_v,
                                                   float* __restrict__ out) {
    int tid = blockIdx.x * 256 + threadIdx.x;
    int v = tid >> 5;
    int f4 = (tid & 31) * 4;
    float* row = out + (size_t)v * 1536;
    const unsigned* rowu = (const unsigned*)row;
    float degf = (float)deg_v[v];
    float4 L0v = *(const float4*)(X + (size_t)v * FEAT + f4);
    float l0[4] = {L0v.x, L0v.y, L0v.z, L0v.w};
    float L[5][4];
#pragma unroll
    for (int sl = 0; sl < 5; ++sl) {
        unsigned d0 = rowu[(sl + 1) * 256 + (f4 >> 1)];
        unsigned d1 = rowu[(sl + 1) * 256 + (f4 >> 1) + 1];
        L[sl][0] = hlo(d0) * degf;
        L[sl][1] = hhi(d0) * degf;
        L[sl][2] = hlo(d1) * degf;
        L[sl][3] = hhi(d1) * degf;
    }
    float wv[6][4];
#pragma unroll
    for (int j = 0; j < 4; ++j) {
        wv[0][j] = l0[j] - L[0][j];
        wv[1][j] = L[0][j] - L[1][j];
        wv[2][j] = L[1][j] - L[2][j];
        wv[3][j] = L[2][j] - L[3][j];
        wv[4][j] = L[3][j] - L[4][j];
        wv[5][j] = L[4][j];
    }
    __syncthreads();
#pragma unroll
    for (int r = 0; r < 6; ++r) {
        float4 pp, mm;
        pp.x = fmaxf(wv[r][0], 0.f); mm.x = fmaxf(-wv[r][0], 0.f);
        pp.y = fmaxf(wv[r][1], 0.f); mm.y = fmaxf(-wv[r][1], 0.f);
        pp.z = fmaxf(wv[r][2], 0.f); mm.z = fmaxf(-wv[r][2], 0.f);
        pp.w = fmaxf(wv[r][3], 0.f); mm.w = fmaxf(-wv[r][3], 0.f);
        *(float4*)(row + r * 256 + f4) = pp;
        *(float4*)(row + r * 256 + 128 + f4) = mm;
    }
}

// ---------------- launch ----------------

extern "C" void kernel_launch(void* const* d_in, const int* in_sizes, int n_in,
                              void* d_out, int out_size, void* d_ws, size_t ws_size,
                              hipStream_t stream) {
    const float* X = (const float*)d_in[0];
    const int* vids = (const int*)d_in[1];
    const int* eids = (const int*)d_in[2];
    const int NNZ = in_sizes[1];         // 1048576
    const int V = in_sizes[0] / FEAT;    // 65536
    const int E = 16384;                 // num_e
    float* out = (float*)d_out;

    const int NBRE_CAP = NNZ + E * 8;    // edge lists, CHUNK=8 padding
    const int NBRV_CAP = NNZ + V * 4;    // vertex lists, CHUNK=4 padding

    char* w = (char*)d_ws;
    size_t o = 0;
    auto take = [&](size_t bytes) {
        void* p = (void*)(w + o);
        o = (o + bytes + 255) & ~(size_t)255;
        return p;
    };
    int* deg_v = (int*)take((size_t)(V + E) * 4);  // deg_v, deg_e contiguous
    int* deg_e = deg_v + V;
    int* off_e = (int*)take((size_t)(E + 1) * 4);
    int* off_v = (int*)take((size_t)(V + 1) * 4);
    int* cur_e = (int*)take((size_t)E * 4);
    int* cur_v = (int*)take((size_t)V * 4);
    float* inv_e = (float*)take((size_t)E * 4);
    float* inv_v = (float*)take((size_t)V * 4);
    int* e_nbr_v = (int*)take((size_t)NBRE_CAP * 4);           // edge segs -> vertex rows
    int* v_nbr_e = (int*)take((size_t)NBRV_CAP * 4);           // vertex segs -> edge rows
    unsigned* xs = (unsigned*)take((size_t)(V + 1) * 64 * 4);  // fp16x2 [V+1][64]
    unsigned* es = (unsigned*)take((size_t)(E + 1) * 64 * 4);  // fp16x2 [E+1][64]
    (void)ws_size;
    (void)n_in;
    (void)out_size;

    // 1) degrees
    hipMemsetAsync(deg_v, 0, (size_t)(V + E) * 4, stream);
    count_deg<<<(NNZ + 255) / 256, 256, 0, stream>>>(vids, eids, deg_v, deg_e, NNZ);

    // 2) padded offsets + cursors + inverse true degrees
    scan_pad<16384, 1024, 8><<<1, 1024, 0, stream>>>(deg_e, off_e, cur_e, inv_e);
    scan_pad<65536, 1024, 4><<<1, 1024, 0, stream>>>(deg_v, off_v, cur_v, inv_v);

    // 3) dummy-fill padded lists (dummy -> zero row), zero dummy rows
    {
        int mx = NBRV_CAP > NBRE_CAP ? NBRV_CAP : NBRE_CAP;
        init_pad<<<(mx + 255) / 256, 256, 0, stream>>>(e_nbr_v, NBRE_CAP, V,
                                                       v_nbr_e, NBRV_CAP, E,
                                                       xs + (size_t)V * 64,
                                                       es + (size_t)E * 64);
    }

    // 4) adjacency lists (real entries; padded tails keep dummy)
    fill_csr<<<(NNZ + 255) / 256, 256, 0, stream>>>(vids, eids, cur_v, cur_e, v_nbr_e, e_nbr_v, NNZ);

    // 5) xs = fp16(X * inv_v)
    prescale<<<V * 64 / 256, 256, 0, stream>>>(X, inv_v, xs);

    // 6) 16 diffusion steps; checkpoints k in {1,2,4,8,16} also write the packed
    //    fp16 scaled level into out[v, slot, dwords 0:64] (recovered by *deg_v).
    for (int k = 1; k <= 16; ++k) {
        gather4<8, 1><<<E / 4, 256, 0, stream>>>(xs, off_e, e_nbr_v, inv_e, es, nullptr, E);
        unsigned* ck = nullptr;
        if (k == 1) ck = (unsigned*)out + 1 * 256;
        else if (k == 2) ck = (unsigned*)out + 2 * 256;
        else if (k == 4) ck = (unsigned*)out + 3 * 256;
        else if (k == 8) ck = (unsigned*)out + 4 * 256;
        else if (k == 16) ck = (unsigned*)out + 5 * 256;
        gather4<4, 4><<<V / 16, 256, 0, stream>>>(es, off_v, v_nbr_e, inv_v, xs, ck, V);
    }

    // 7) wavelet combine + relu split, in place over out
    wavelet_out<<<V * 32 / 256, 256, 0, stream>>>(X, deg_v, out);
}